// Round 10
// baseline (643.576 us; speedup 1.0000x reference)
//
#include <hip/hip_runtime.h>

#define BATCH 256
#define TSTEPS 2048
#define INSZ 64
#define HID 128
#define OUTSZ 64
#define NTHR 512
#define CHUNK 32                 // timesteps of x per staging buffer (8KB)
#define NCHUNK (TSTEPS / CHUNK)  // 64

typedef float v2f __attribute__((ext_vector_type(2)));
typedef float v4f __attribute__((ext_vector_type(4)));

#define AS1 __attribute__((address_space(1)))
#define AS3 __attribute__((address_space(3)))

// DPP cross-lane move (VALU pipe). Patterns stay within a 16-lane row.
template <int CTRL>
__device__ __forceinline__ float dppf(float v) {
  return __int_as_float(__builtin_amdgcn_update_dpp(
      0, __float_as_int(v), CTRL, 0xF, 0xF, true));
}
#define DPP_XOR1 0xB1    // quad_perm:[1,0,3,2]
#define DPP_XOR2 0x4E    // quad_perm:[2,3,0,1]
#define DPP_XOR15 0x140  // row_mirror (lane ^ 15 within 16)
#define DPP_XOR8 0x128   // row_ror:8  (lane ^ 8  within 16)

// lane ^ 16 exchange: ds_swizzle BitMode xor_mask=0x10 (in-register DS-pipe op,
// stays within each 32-lane half; documented pattern 0x401F)
__device__ __forceinline__ float swz16(float v) {
  return __int_as_float(__builtin_amdgcn_ds_swizzle(__float_as_int(v), 0x401F));
}

// guaranteed packed f32 math (2 MACs / instr)
__device__ __forceinline__ v2f pk_mul(v2f a, v2f b) {
  v2f d; asm("v_pk_mul_f32 %0, %1, %2" : "=v"(d) : "v"(a), "v"(b)); return d;
}
__device__ __forceinline__ v2f pk_fma(v2f a, v2f b, v2f c) {
  v2f d; asm("v_pk_fma_f32 %0, %1, %2, %3" : "=v"(d) : "v"(a), "v"(b), "v"(c)); return d;
}

// 512 threads / 8 waves per batch element (2 waves per SIMD).
//   k-group s = lane&31 (lane bits 0-4):
//       h-k range [4s, 4s+4)  -> ONE ds_read_b128 per thread per step
//       x-k range [2s, 2s+2)  -> ONE ds_read_b64  per thread per step
//   j-group g = (wave<<1) | lane_bit5  in [0,16); 8 rows per thread.
// Slot m holds row j = 8g + (m ^ f),  f = (n0^n2) | ((n1^n2)<<1) | (b4<<2)
// (n_i = lane bits 0..3, b4 = lane bit 4). Reduce over the 32-lane k-space:
// stages xor1, xor2 (slot pairs, DPP), xor16 (ds_swizzle 0x401F), xor15
// (row_mirror), xor8 (row_ror:8). Verified: every lane ends with the full
// 128-k sum of row j = 8g + f; lanes (lane&12)==0 write 8 distinct j per g.
// h padded: addr = k + (k>>3)*4. x staged global->LDS in 32-step chunks;
// barriers are raw s_barrier + lgkmcnt(0); vmcnt drained once per chunk.
__launch_bounds__(NTHR, 1)
__global__ void rnn_kt4b_kernel(const float* __restrict__ x,
                                const float* __restrict__ Wx_w,
                                const float* __restrict__ Wx_b,
                                const float* __restrict__ Wh_w,
                                const float* __restrict__ Wh_b,
                                const float* __restrict__ fc_w,
                                const float* __restrict__ fc_b,
                                float* __restrict__ out) {
  const int b = blockIdx.x;
  const int tid = threadIdx.x;
  const int lane = tid & 63;
  const int wave = tid >> 6;
  const int n0 = lane & 1, n1 = (lane >> 1) & 1, n2 = (lane >> 2) & 1;
  const int b4 = (lane >> 4) & 1;
  const int s = lane & 31;                          // k-group 0..31
  const int g = (wave << 1) | ((lane >> 5) & 1);    // j-group 0..15
  const int f = (n0 ^ n2) | ((n1 ^ n2) << 1) | (b4 << 2);
  const int jf = 8 * g + f;                 // the j this lane finalizes
  const int jp = 12 * g + f;                // padded write index
  const int hoff = 4 * s + ((s >> 1) << 2); // padded read offset of k=4s

  __shared__ __align__(16) float hA[192], hB[192];        // padded h buffers
  __shared__ __align__(16) float xsm[2][CHUNK * INSZ];    // 2 x 8KB

  // ---- weights: slot m holds row j = 8g + (m ^ f) ----
  v2f wh2[8][2], wx2[8];
#pragma unroll
  for (int m = 0; m < 8; ++m) {
    const int row = 8 * g + (m ^ f);
    const float* p = Wh_w + row * HID + 4 * s;
    v4f t0 = *(const v4f*)p;
    wh2[m][0] = (v2f){t0.x, t0.y};
    wh2[m][1] = (v2f){t0.z, t0.w};
    const float* q = Wx_w + row * INSZ + 2 * s;
    wx2[m] = *(const v2f*)q;
  }
  const float bc = Wx_b[jf] + Wh_b[jf];

  const float* xg = x + (size_t)b * TSTEPS * INSZ;

  // ---- init h0 = 0 ----
  if (tid < 192) hA[tid] = 0.f;

  // ---- stage chunk 0: 512 threads x 16B = 8KB ----
  {
    const AS1 float* gp = (const AS1 float*)(xg + tid * 4);
    AS3 float* d = (AS3 float*)(&xsm[0][(tid >> 6) * 256]);
    __builtin_amdgcn_global_load_lds(gp, d, 16, 0, 0);
  }
  asm volatile("s_waitcnt vmcnt(0) lgkmcnt(0)\ns_barrier" ::: "memory");

  // ---- recurrence ----
  for (int tc = 0; tc < NCHUNK; ++tc) {
    if (tc + 1 < NCHUNK) {
      const AS1 float* gp =
          (const AS1 float*)(xg + (size_t)(tc + 1) * CHUNK * INSZ + tid * 4);
      AS3 float* d = (AS3 float*)(&xsm[(tc + 1) & 1][(tid >> 6) * 256]);
      __builtin_amdgcn_global_load_lds(gp, d, 16, 0, 0);
    }
    const float* xc = xsm[tc & 1];
    v2f xcur = *(const v2f*)&xc[2 * s];  // ts = 0 (buffer just drained)

#pragma unroll
    for (int ts = 0; ts < CHUNK; ++ts) {
      const float* hin = (ts & 1) ? hB : hA;  // parity static (CHUNK even)
      float* hout = (ts & 1) ? hA : hB;

      // the ONLY h load: one b128 (4 floats = this thread's whole k-range)
      v4f h0 = *(const v4f*)(hin + hoff);

      // prefetch next step's x (no h dependency; latency hidden a full step)
      v2f xnext;
      if (ts + 1 < CHUNK) xnext = *(const v2f*)&xc[(ts + 1) * INSZ + 2 * s];

      v2f hx0 = (v2f){h0.x, h0.y}, hx1 = (v2f){h0.z, h0.w};

      // 24 packed MACs: x-part first (xcur ready from last step)
      float a0, a1, a2, a3, a4, a5, a6, a7;
      float* aptr[8] = {&a0, &a1, &a2, &a3, &a4, &a5, &a6, &a7};
#pragma unroll
      for (int m = 0; m < 8; ++m) {
        v2f acc = pk_mul(wx2[m], xcur);
        acc = pk_fma(wh2[m][0], hx0, acc);
        acc = pk_fma(wh2[m][1], hx1, acc);
        *aptr[m] = acc.x + acc.y;
      }

      // 5-stage butterfly reduce-scatter over the 32-lane k-space
      float b0 = a0 + dppf<DPP_XOR1>(a1);
      float b1 = a2 + dppf<DPP_XOR1>(a3);
      float b2 = a4 + dppf<DPP_XOR1>(a5);
      float b3 = a6 + dppf<DPP_XOR1>(a7);
      float c0 = b0 + dppf<DPP_XOR2>(b1);
      float c1 = b2 + dppf<DPP_XOR2>(b3);
      float d0 = c0 + swz16(c1);
      float e0 = d0 + dppf<DPP_XOR15>(d0);
      float z  = e0 + dppf<DPP_XOR8>(e0);

      // tanh(z+bc) = 1 - 2/(exp2(2*(z+bc)*log2e)+1)
      z += bc;
      float e = __builtin_amdgcn_exp2f(z * 2.8853900817779268f);
      float hn = fmaf(-2.f, __builtin_amdgcn_rcpf(e + 1.f), 1.f);

      if ((lane & 12) == 0) hout[jp] = hn;  // 16 writers/wave, distinct j's

      if (ts + 1 < CHUNK) xcur = xnext;

      if (ts == CHUNK - 1) {
        // vmcnt drain folded here: next chunk's loads are 31 steps old -> free
        asm volatile("s_waitcnt vmcnt(0) lgkmcnt(0)\ns_barrier" ::: "memory");
      } else {
        asm volatile("s_waitcnt lgkmcnt(0)\ns_barrier" ::: "memory");
      }
    }
  }

  // ---- epilogue: logits + softmax over 64, one wave; final h in hA ----
  if (tid < 64) {
    float acc = fc_b[tid];
    const float* fr = fc_w + tid * HID;
#pragma unroll
    for (int k8 = 0; k8 < 16; ++k8) {
      v4f w0 = *(const v4f*)(fr + 8 * k8);
      v4f w1 = *(const v4f*)(fr + 8 * k8 + 4);
      const float* hh = &hA[12 * k8];
      v4f p0 = *(const v4f*)hh;
      v4f p1 = *(const v4f*)(hh + 4);
      acc = fmaf(w0.x, p0.x, acc);
      acc = fmaf(w0.y, p0.y, acc);
      acc = fmaf(w0.z, p0.z, acc);
      acc = fmaf(w0.w, p0.w, acc);
      acc = fmaf(w1.x, p1.x, acc);
      acc = fmaf(w1.y, p1.y, acc);
      acc = fmaf(w1.z, p1.z, acc);
      acc = fmaf(w1.w, p1.w, acc);
    }
    float m = acc;
#pragma unroll
    for (int off = 32; off >= 1; off >>= 1) m = fmaxf(m, __shfl_xor(m, off, 64));
    float e = __builtin_amdgcn_exp2f((acc - m) * 1.4426950408889634f);
    float ssum = e;
#pragma unroll
    for (int off = 32; off >= 1; off >>= 1) ssum += __shfl_xor(ssum, off, 64);
    out[b * OUTSZ + tid] = e / ssum;
  }
}

extern "C" void kernel_launch(void* const* d_in, const int* in_sizes, int n_in,
                              void* d_out, int out_size, void* d_ws, size_t ws_size,
                              hipStream_t stream) {
  const float* x    = (const float*)d_in[0];
  const float* Wx_w = (const float*)d_in[1];
  const float* Wx_b = (const float*)d_in[2];
  const float* Wh_w = (const float*)d_in[3];
  const float* Wh_b = (const float*)d_in[4];
  const float* fc_w = (const float*)d_in[5];
  const float* fc_b = (const float*)d_in[6];
  float* out = (float*)d_out;

  rnn_kt4b_kernel<<<BATCH, NTHR, 0, stream>>>(x, Wx_w, Wx_b, Wh_w, Wh_b, fc_w, fc_b, out);
}

// Round 11
// 591.718 us; speedup vs baseline: 1.0876x; 1.0876x over previous
//
#include <hip/hip_runtime.h>

#define BATCH 256
#define TSTEPS 2048
#define INSZ 64
#define HID 128
#define OUTSZ 64
#define NTHR 512
#define CHUNK 32                 // timesteps of x per staging buffer (8KB)
#define NCHUNK (TSTEPS / CHUNK)  // 64

typedef float v2f __attribute__((ext_vector_type(2)));
typedef float v4f __attribute__((ext_vector_type(4)));

#define AS1 __attribute__((address_space(1)))
#define AS3 __attribute__((address_space(3)))

// DPP cross-lane move (VALU pipe). Patterns stay within a 16-lane row.
template <int CTRL>
__device__ __forceinline__ float dppf(float v) {
  return __int_as_float(__builtin_amdgcn_update_dpp(
      0, __float_as_int(v), CTRL, 0xF, 0xF, true));
}
#define DPP_XOR1 0xB1    // quad_perm:[1,0,3,2]
#define DPP_XOR2 0x4E    // quad_perm:[2,3,0,1]
#define DPP_XOR15 0x140  // row_mirror (lane ^ 15 within 16)
#define DPP_XOR8 0x128   // row_ror:8  (lane ^ 8  within 16)

// guaranteed packed f32 math (2 MACs / instr)
__device__ __forceinline__ v2f pk_mul(v2f a, v2f b) {
  v2f d; asm("v_pk_mul_f32 %0, %1, %2" : "=v"(d) : "v"(a), "v"(b)); return d;
}
__device__ __forceinline__ v2f pk_fma(v2f a, v2f b, v2f c) {
  v2f d; asm("v_pk_fma_f32 %0, %1, %2, %3" : "=v"(d) : "v"(a), "v"(b), "v"(c)); return d;
}

// 512 threads / 8 waves per batch element (2 waves per SIMD). Round-6 (best)
// structure + x-part software-pipelined across the barrier:
//   k-group s = tid&15 : h-k range [8s,8s+8), x-k range [4s,4s+4)
//   j-group g = tid>>4 : j range [4g, 4g+4)   (32 j-groups)
// Slot m holds row j = 4g + (m ^ c),  c = (s0^s2)|((s1^s2)<<1); DPP butterfly
// reduce (xor1 slots, xor2 slots, xor15, xor8 lanes); lanes s<4 write h.
// h padded: addr = k + (k>>3)*4 (KT=8 is bank-optimal: 16 distinct b128 addrs
// x 4-lane broadcast = 2-way = free; KT=4 was measured 4-way-conflicted).
// xacc[m] = Wx x_{t+1} is computed at the END of step t from the prefetched
// xnext (off the post-barrier critical path); post-barrier chain is only
// h-read -> 4 pk_fma -> reduce -> tanh -> write.
__launch_bounds__(NTHR, 1)
__global__ void rnn_pipe_kernel(const float* __restrict__ x,
                                const float* __restrict__ Wx_w,
                                const float* __restrict__ Wx_b,
                                const float* __restrict__ Wh_w,
                                const float* __restrict__ Wh_b,
                                const float* __restrict__ fc_w,
                                const float* __restrict__ fc_b,
                                float* __restrict__ out) {
  const int b = blockIdx.x;
  const int tid = threadIdx.x;
  const int s = tid & 15;  // k-group (= lane&15)
  const int g = tid >> 4;  // j-group (0..31)
  const int s0 = s & 1, s1 = (s >> 1) & 1, s2 = (s >> 2) & 1;
  const int c = (s0 ^ s2) | ((s1 ^ s2) << 1);
  const int jf = 4 * g + c;                  // the j this lane finalizes
  const int jp = jf + ((jf >> 3) << 2);      // padded write index

  __shared__ __align__(16) float hA[192], hB[192];        // padded h buffers
  __shared__ __align__(16) float xsm[2][CHUNK * INSZ];    // 2 x 8KB

  // ---- weights: slot m holds row j = 4g + (m ^ c) ----
  v2f wh2[4][4], wx2[4][2];
#pragma unroll
  for (int m = 0; m < 4; ++m) {
    const int row = 4 * g + (m ^ c);
    const float* p = Wh_w + row * HID + 8 * s;
    v4f t0 = *(const v4f*)p;
    v4f t1 = *(const v4f*)(p + 4);
    wh2[m][0] = (v2f){t0.x, t0.y};
    wh2[m][1] = (v2f){t0.z, t0.w};
    wh2[m][2] = (v2f){t1.x, t1.y};
    wh2[m][3] = (v2f){t1.z, t1.w};
    const float* q = Wx_w + row * INSZ + 4 * s;
    v4f t2 = *(const v4f*)q;
    wx2[m][0] = (v2f){t2.x, t2.y};
    wx2[m][1] = (v2f){t2.z, t2.w};
  }
  const float bc = Wx_b[jf] + Wh_b[jf];

  const float* xg = x + (size_t)b * TSTEPS * INSZ;

  // ---- init h0 = 0 ----
  if (tid < 192) hA[tid] = 0.f;

  // ---- stage chunk 0: 512 threads x 16B = 8KB ----
  {
    const AS1 float* gp = (const AS1 float*)(xg + tid * 4);
    AS3 float* d = (AS3 float*)(&xsm[0][(tid >> 6) * 256]);
    __builtin_amdgcn_global_load_lds(gp, d, 16, 0, 0);
  }
  asm volatile("s_waitcnt vmcnt(0) lgkmcnt(0)\ns_barrier" ::: "memory");

  // ---- recurrence ----
  for (int tc = 0; tc < NCHUNK; ++tc) {
    // re-pin weights to arch VGPRs once per chunk
#pragma unroll
    for (int m = 0; m < 4; ++m) {
      asm("" : "+v"(wh2[m][0]), "+v"(wh2[m][1]), "+v"(wh2[m][2]), "+v"(wh2[m][3]));
      asm("" : "+v"(wx2[m][0]), "+v"(wx2[m][1]));
    }
    if (tc + 1 < NCHUNK) {
      const AS1 float* gp =
          (const AS1 float*)(xg + (size_t)(tc + 1) * CHUNK * INSZ + tid * 4);
      AS3 float* d = (AS3 float*)(&xsm[(tc + 1) & 1][(tid >> 6) * 256]);
      __builtin_amdgcn_global_load_lds(gp, d, 16, 0, 0);
    }
    const float* xc = xsm[tc & 1];

    // chunk-top: load x[ts=0] and precompute its xacc (in the shadow of the
    // barrier that just retired; once per 32 steps)
    v2f xacc0, xacc1, xacc2, xacc3;
    {
      v4f xcur = *(const v4f*)&xc[4 * s];
      v2f xx0 = (v2f){xcur.x, xcur.y}, xx1 = (v2f){xcur.z, xcur.w};
      xacc0 = pk_mul(wx2[0][0], xx0); xacc0 = pk_fma(wx2[0][1], xx1, xacc0);
      xacc1 = pk_mul(wx2[1][0], xx0); xacc1 = pk_fma(wx2[1][1], xx1, xacc1);
      xacc2 = pk_mul(wx2[2][0], xx0); xacc2 = pk_fma(wx2[2][1], xx1, xacc2);
      xacc3 = pk_mul(wx2[3][0], xx0); xacc3 = pk_fma(wx2[3][1], xx1, xacc3);
    }

#pragma unroll
    for (int ts = 0; ts < CHUNK; ++ts) {
      const float* hin = (ts & 1) ? hB : hA;  // parity static (CHUNK even)
      float* hout = (ts & 1) ? hA : hB;

      // h reads at step head (the only exposed LDS latency)
      const float* hp = hin + 12 * s;
      v4f h0 = *(const v4f*)hp;
      v4f h1 = *(const v4f*)(hp + 4);

      // prefetch next step's x (independent of h; consumed after the reduce)
      v4f xnext;
      if (ts + 1 < CHUNK) xnext = *(const v4f*)&xc[(ts + 1) * INSZ + 4 * s];

      v2f hx0 = (v2f){h0.x, h0.y}, hx1 = (v2f){h0.z, h0.w};
      v2f hx2 = (v2f){h1.x, h1.y}, hx3 = (v2f){h1.z, h1.w};

      // post-barrier MACs: h-part only, accumulating onto precomputed xacc
      float a0, a1, a2, a3;
      {
        v2f acc = pk_fma(wh2[0][0], hx0, xacc0);
        acc = pk_fma(wh2[0][1], hx1, acc);
        acc = pk_fma(wh2[0][2], hx2, acc);
        acc = pk_fma(wh2[0][3], hx3, acc);
        a0 = acc.x + acc.y;
      }
      {
        v2f acc = pk_fma(wh2[1][0], hx0, xacc1);
        acc = pk_fma(wh2[1][1], hx1, acc);
        acc = pk_fma(wh2[1][2], hx2, acc);
        acc = pk_fma(wh2[1][3], hx3, acc);
        a1 = acc.x + acc.y;
      }
      {
        v2f acc = pk_fma(wh2[2][0], hx0, xacc2);
        acc = pk_fma(wh2[2][1], hx1, acc);
        acc = pk_fma(wh2[2][2], hx2, acc);
        acc = pk_fma(wh2[2][3], hx3, acc);
        a2 = acc.x + acc.y;
      }
      {
        v2f acc = pk_fma(wh2[3][0], hx0, xacc3);
        acc = pk_fma(wh2[3][1], hx1, acc);
        acc = pk_fma(wh2[3][2], hx2, acc);
        acc = pk_fma(wh2[3][3], hx3, acc);
        a3 = acc.x + acc.y;
      }

      // DPP butterfly reduce-scatter over the 16-lane k-group
      float b0 = a0 + dppf<DPP_XOR1>(a1);
      float b1 = a2 + dppf<DPP_XOR1>(a3);
      float w  = b0 + dppf<DPP_XOR2>(b1);
      float u  = w + dppf<DPP_XOR15>(w);
      float z  = u + dppf<DPP_XOR8>(u);

      // tanh(z+bc) = 1 - 2/(exp2(2*(z+bc)*log2e)+1)
      z += bc;
      float e = __builtin_amdgcn_exp2f(z * 2.8853900817779268f);
      float hn = fmaf(-2.f, __builtin_amdgcn_rcpf(e + 1.f), 1.f);

      if (s < 4) hout[jp] = hn;  // lanes s=0..3 hold j=4g+s

      // pipeline: next step's x-MACs, off the post-barrier critical path
      if (ts + 1 < CHUNK) {
        v2f xx0 = (v2f){xnext.x, xnext.y}, xx1 = (v2f){xnext.z, xnext.w};
        xacc0 = pk_mul(wx2[0][0], xx0); xacc0 = pk_fma(wx2[0][1], xx1, xacc0);
        xacc1 = pk_mul(wx2[1][0], xx0); xacc1 = pk_fma(wx2[1][1], xx1, xacc1);
        xacc2 = pk_mul(wx2[2][0], xx0); xacc2 = pk_fma(wx2[2][1], xx1, xacc2);
        xacc3 = pk_mul(wx2[3][0], xx0); xacc3 = pk_fma(wx2[3][1], xx1, xacc3);
      }

      if (ts == CHUNK - 1) {
        // vmcnt drain folded here: next chunk's loads are 31 steps old -> free
        asm volatile("s_waitcnt vmcnt(0) lgkmcnt(0)\ns_barrier" ::: "memory");
      } else {
        asm volatile("s_waitcnt lgkmcnt(0)\ns_barrier" ::: "memory");
      }
    }
  }

  // ---- epilogue: logits + softmax over 64, one wave; final h in hA ----
  if (tid < 64) {
    float acc = fc_b[tid];
    const float* fr = fc_w + tid * HID;
#pragma unroll
    for (int k8 = 0; k8 < 16; ++k8) {
      v4f w0 = *(const v4f*)(fr + 8 * k8);
      v4f w1 = *(const v4f*)(fr + 8 * k8 + 4);
      const float* hh = &hA[12 * k8];
      v4f p0 = *(const v4f*)hh;
      v4f p1 = *(const v4f*)(hh + 4);
      acc = fmaf(w0.x, p0.x, acc);
      acc = fmaf(w0.y, p0.y, acc);
      acc = fmaf(w0.z, p0.z, acc);
      acc = fmaf(w0.w, p0.w, acc);
      acc = fmaf(w1.x, p1.x, acc);
      acc = fmaf(w1.y, p1.y, acc);
      acc = fmaf(w1.z, p1.z, acc);
      acc = fmaf(w1.w, p1.w, acc);
    }
    float m = acc;
#pragma unroll
    for (int off = 32; off >= 1; off >>= 1) m = fmaxf(m, __shfl_xor(m, off, 64));
    float e = __builtin_amdgcn_exp2f((acc - m) * 1.4426950408889634f);
    float ssum = e;
#pragma unroll
    for (int off = 32; off >= 1; off >>= 1) ssum += __shfl_xor(ssum, off, 64);
    out[b * OUTSZ + tid] = e / ssum;
  }
}

extern "C" void kernel_launch(void* const* d_in, const int* in_sizes, int n_in,
                              void* d_out, int out_size, void* d_ws, size_t ws_size,
                              hipStream_t stream) {
  const float* x    = (const float*)d_in[0];
  const float* Wx_w = (const float*)d_in[1];
  const float* Wx_b = (const float*)d_in[2];
  const float* Wh_w = (const float*)d_in[3];
  const float* Wh_b = (const float*)d_in[4];
  const float* fc_w = (const float*)d_in[5];
  const float* fc_b = (const float*)d_in[6];
  float* out = (float*)d_out;

  rnn_pipe_kernel<<<BATCH, NTHR, 0, stream>>>(x, Wx_w, Wx_b, Wh_w, Wh_b, fc_w, fc_b, out);
}

// Round 12
// 591.654 us; speedup vs baseline: 1.0878x; 1.0001x over previous
//
#include <hip/hip_runtime.h>

#define BATCH 256
#define TSTEPS 2048
#define INSZ 64
#define HID 128
#define OUTSZ 64
#define NTHR 512
#define CHUNK 32                 // timesteps of x per staging buffer (8KB)
#define NCHUNK (TSTEPS / CHUNK)  // 64

typedef float v2f __attribute__((ext_vector_type(2)));
typedef float v4f __attribute__((ext_vector_type(4)));

#define AS1 __attribute__((address_space(1)))
#define AS3 __attribute__((address_space(3)))

// DPP cross-lane move (VALU pipe). Patterns stay within a 16-lane row.
template <int CTRL>
__device__ __forceinline__ float dppf(float v) {
  return __int_as_float(__builtin_amdgcn_update_dpp(
      0, __float_as_int(v), CTRL, 0xF, 0xF, true));
}
#define DPP_XOR1 0xB1    // quad_perm:[1,0,3,2]
#define DPP_XOR2 0x4E    // quad_perm:[2,3,0,1]
#define DPP_XOR15 0x140  // row_mirror (lane ^ 15 within 16)
#define DPP_XOR8 0x128   // row_ror:8  (lane ^ 8  within 16)

// guaranteed packed f32 math (2 MACs / instr)
__device__ __forceinline__ v2f pk_mul(v2f a, v2f b) {
  v2f d; asm("v_pk_mul_f32 %0, %1, %2" : "=v"(d) : "v"(a), "v"(b)); return d;
}
__device__ __forceinline__ v2f pk_fma(v2f a, v2f b, v2f c) {
  v2f d; asm("v_pk_fma_f32 %0, %1, %2, %3" : "=v"(d) : "v"(a), "v"(b), "v"(c)); return d;
}

// 512 threads / 8 waves per batch element (2 waves per SIMD) — the measured
// optimum across 11 structural variants (538us; 1-wave 3563, 4-wave 1270,
// opaque-global-x 613, KT=4 643, x-pipelined 592).
//   k-group s = tid&15 : h-k range [8s,8s+8), x-k range [4s,4s+4)
//   j-group g = tid>>4 : j range [4g, 4g+4)   (32 j-groups)
// Slot m holds row j = 4g + (m ^ c),  c = (s0^s2)|((s1^s2)<<1); DPP butterfly
// reduce (xor1 slots, xor2 slots, xor15, xor8 lanes); lanes s<4 write h.
// h padded: addr = k + (k>>3)*4 (KT=8 is bank-optimal: 16 distinct b128 addrs
// x 4-lane broadcast = 2-way = free). x staged global->LDS in 32-step chunks;
// barriers are raw s_barrier + lgkmcnt(0); vmcnt drained once per chunk
// (loads 31 steps old -> free).
__launch_bounds__(NTHR, 1)
__global__ void rnn_dpp512_kernel(const float* __restrict__ x,
                                  const float* __restrict__ Wx_w,
                                  const float* __restrict__ Wx_b,
                                  const float* __restrict__ Wh_w,
                                  const float* __restrict__ Wh_b,
                                  const float* __restrict__ fc_w,
                                  const float* __restrict__ fc_b,
                                  float* __restrict__ out) {
  const int b = blockIdx.x;
  const int tid = threadIdx.x;
  const int s = tid & 15;  // k-group (= lane&15)
  const int g = tid >> 4;  // j-group (0..31)
  const int s0 = s & 1, s1 = (s >> 1) & 1, s2 = (s >> 2) & 1;
  const int c = (s0 ^ s2) | ((s1 ^ s2) << 1);
  const int jf = 4 * g + c;                  // the j this lane finalizes
  const int jp = jf + ((jf >> 3) << 2);      // padded write index

  __shared__ __align__(16) float hA[192], hB[192];        // padded h buffers
  __shared__ __align__(16) float xsm[2][CHUNK * INSZ];    // 2 x 8KB

  // ---- weights: slot m holds row j = 4g + (m ^ c) ----
  v2f wh2[4][4], wx2[4][2];
#pragma unroll
  for (int m = 0; m < 4; ++m) {
    const int row = 4 * g + (m ^ c);
    const float* p = Wh_w + row * HID + 8 * s;
    v4f t0 = *(const v4f*)p;
    v4f t1 = *(const v4f*)(p + 4);
    wh2[m][0] = (v2f){t0.x, t0.y};
    wh2[m][1] = (v2f){t0.z, t0.w};
    wh2[m][2] = (v2f){t1.x, t1.y};
    wh2[m][3] = (v2f){t1.z, t1.w};
    const float* q = Wx_w + row * INSZ + 4 * s;
    v4f t2 = *(const v4f*)q;
    wx2[m][0] = (v2f){t2.x, t2.y};
    wx2[m][1] = (v2f){t2.z, t2.w};
  }
  const float bc = Wx_b[jf] + Wh_b[jf];

  const float* xg = x + (size_t)b * TSTEPS * INSZ;

  // ---- init h0 = 0 ----
  if (tid < 192) hA[tid] = 0.f;

  // ---- stage chunk 0: 512 threads x 16B = 8KB ----
  {
    const AS1 float* gp = (const AS1 float*)(xg + tid * 4);
    AS3 float* d = (AS3 float*)(&xsm[0][(tid >> 6) * 256]);
    __builtin_amdgcn_global_load_lds(gp, d, 16, 0, 0);
  }
  asm volatile("s_waitcnt vmcnt(0) lgkmcnt(0)\ns_barrier" ::: "memory");

  // ---- recurrence ----
  for (int tc = 0; tc < NCHUNK; ++tc) {
    // re-pin weights to arch VGPRs once per chunk (blocks AGPR shuttling)
#pragma unroll
    for (int m = 0; m < 4; ++m) {
      asm("" : "+v"(wh2[m][0]), "+v"(wh2[m][1]), "+v"(wh2[m][2]), "+v"(wh2[m][3]));
      asm("" : "+v"(wx2[m][0]), "+v"(wx2[m][1]));
    }
    if (tc + 1 < NCHUNK) {
      const AS1 float* gp =
          (const AS1 float*)(xg + (size_t)(tc + 1) * CHUNK * INSZ + tid * 4);
      AS3 float* d = (AS3 float*)(&xsm[(tc + 1) & 1][(tid >> 6) * 256]);
      __builtin_amdgcn_global_load_lds(gp, d, 16, 0, 0);
    }
    const float* xc = xsm[tc & 1];
    v4f xcur = *(const v4f*)&xc[4 * s];  // ts = 0 (buffer just drained)

#pragma unroll
    for (int ts = 0; ts < CHUNK; ++ts) {
      const float* hin = (ts & 1) ? hB : hA;  // parity static (CHUNK even)
      float* hout = (ts & 1) ? hA : hB;

      // h reads at step head (the only exposed LDS latency)
      const float* hp = hin + 12 * s;
      v4f h0 = *(const v4f*)hp;
      v4f h1 = *(const v4f*)(hp + 4);

      // prefetch next step's x (no h dependency; latency hidden a full step)
      v4f xnext;
      if (ts + 1 < CHUNK) xnext = *(const v4f*)&xc[(ts + 1) * INSZ + 4 * s];

      v2f xx0 = (v2f){xcur.x, xcur.y}, xx1 = (v2f){xcur.z, xcur.w};
      v2f hx0 = (v2f){h0.x, h0.y}, hx1 = (v2f){h0.z, h0.w};
      v2f hx2 = (v2f){h1.x, h1.y}, hx3 = (v2f){h1.z, h1.w};

      float a0, a1, a2, a3;
      float* aptr[4] = {&a0, &a1, &a2, &a3};
#pragma unroll
      for (int m = 0; m < 4; ++m) {
        v2f acc = pk_mul(wx2[m][0], xx0);          // x-part first (ready early)
        acc = pk_fma(wx2[m][1], xx1, acc);
        acc = pk_fma(wh2[m][0], hx0, acc);
        acc = pk_fma(wh2[m][1], hx1, acc);
        acc = pk_fma(wh2[m][2], hx2, acc);
        acc = pk_fma(wh2[m][3], hx3, acc);
        *aptr[m] = acc.x + acc.y;
      }

      // DPP butterfly reduce-scatter over the 16-lane k-group
      float b0 = a0 + dppf<DPP_XOR1>(a1);
      float b1 = a2 + dppf<DPP_XOR1>(a3);
      float w  = b0 + dppf<DPP_XOR2>(b1);
      float u  = w + dppf<DPP_XOR15>(w);
      float z  = u + dppf<DPP_XOR8>(u);

      // tanh(z+bc) = 1 - 2/(exp2(2*(z+bc)*log2e)+1)
      z += bc;
      float e = __builtin_amdgcn_exp2f(z * 2.8853900817779268f);
      float hn = fmaf(-2.f, __builtin_amdgcn_rcpf(e + 1.f), 1.f);

      if (s < 4) hout[jp] = hn;  // lanes s=0..3 hold j=4g+s

      if (ts + 1 < CHUNK) xcur = xnext;

      if (ts == CHUNK - 1) {
        // vmcnt drain folded here: next chunk's loads are 31 steps old -> free
        asm volatile("s_waitcnt vmcnt(0) lgkmcnt(0)\ns_barrier" ::: "memory");
      } else {
        asm volatile("s_waitcnt lgkmcnt(0)\ns_barrier" ::: "memory");
      }
    }
  }

  // ---- epilogue: logits + softmax over 64, one wave; final h in hA ----
  if (tid < 64) {
    float acc = fc_b[tid];
    const float* fr = fc_w + tid * HID;
#pragma unroll
    for (int k8 = 0; k8 < 16; ++k8) {
      v4f w0 = *(const v4f*)(fr + 8 * k8);
      v4f w1 = *(const v4f*)(fr + 8 * k8 + 4);
      const float* hh = &hA[12 * k8];
      v4f p0 = *(const v4f*)hh;
      v4f p1 = *(const v4f*)(hh + 4);
      acc = fmaf(w0.x, p0.x, acc);
      acc = fmaf(w0.y, p0.y, acc);
      acc = fmaf(w0.z, p0.z, acc);
      acc = fmaf(w0.w, p0.w, acc);
      acc = fmaf(w1.x, p1.x, acc);
      acc = fmaf(w1.y, p1.y, acc);
      acc = fmaf(w1.z, p1.z, acc);
      acc = fmaf(w1.w, p1.w, acc);
    }
    float m = acc;
#pragma unroll
    for (int off = 32; off >= 1; off >>= 1) m = fmaxf(m, __shfl_xor(m, off, 64));
    float e = __builtin_amdgcn_exp2f((acc - m) * 1.4426950408889634f);
    float ssum = e;
#pragma unroll
    for (int off = 32; off >= 1; off >>= 1) ssum += __shfl_xor(ssum, off, 64);
    out[b * OUTSZ + tid] = e / ssum;
  }
}

extern "C" void kernel_launch(void* const* d_in, const int* in_sizes, int n_in,
                              void* d_out, int out_size, void* d_ws, size_t ws_size,
                              hipStream_t stream) {
  const float* x    = (const float*)d_in[0];
  const float* Wx_w = (const float*)d_in[1];
  const float* Wx_b = (const float*)d_in[2];
  const float* Wh_w = (const float*)d_in[3];
  const float* Wh_b = (const float*)d_in[4];
  const float* fc_w = (const float*)d_in[5];
  const float* fc_b = (const float*)d_in[6];
  float* out = (float*)d_out;

  rnn_dpp512_kernel<<<BATCH, NTHR, 0, stream>>>(x, Wx_w, Wx_b, Wh_w, Wh_b, fc_w, fc_b, out);
}

// Round 13
// 539.218 us; speedup vs baseline: 1.1935x; 1.0972x over previous
//
#include <hip/hip_runtime.h>

#define BATCH 256
#define TSTEPS 2048
#define INSZ 64
#define HID 128
#define OUTSZ 64
#define NTHR 512
#define CHUNK 32                 // timesteps of x per staging buffer (8KB)
#define NCHUNK (TSTEPS / CHUNK)  // 64

typedef float v2f __attribute__((ext_vector_type(2)));
typedef float v4f __attribute__((ext_vector_type(4)));

#define AS1 __attribute__((address_space(1)))
#define AS3 __attribute__((address_space(3)))

// DPP cross-lane move (VALU pipe). Patterns stay within a 16-lane row.
template <int CTRL>
__device__ __forceinline__ float dppf(float v) {
  return __int_as_float(__builtin_amdgcn_update_dpp(
      0, __float_as_int(v), CTRL, 0xF, 0xF, true));
}
#define DPP_XOR1 0xB1    // quad_perm:[1,0,3,2]
#define DPP_XOR2 0x4E    // quad_perm:[2,3,0,1]
#define DPP_XOR15 0x140  // row_mirror (lane ^ 15 within 16)
#define DPP_XOR8 0x128   // row_ror:8  (lane ^ 8  within 16)

// guaranteed packed f32 math (2 MACs / instr)
__device__ __forceinline__ v2f pk_mul(v2f a, v2f b) {
  v2f d; asm("v_pk_mul_f32 %0, %1, %2" : "=v"(d) : "v"(a), "v"(b)); return d;
}
__device__ __forceinline__ v2f pk_fma(v2f a, v2f b, v2f c) {
  v2f d; asm("v_pk_fma_f32 %0, %1, %2, %3" : "=v"(d) : "v"(a), "v"(b), "v"(c)); return d;
}

// 512 threads / 8 waves per batch element (2 waves per SIMD).
//   k-group s = tid&15 : h-k range [8s,8s+8), x-k range [4s,4s+4)
//   j-group g = tid>>4 : j range [4g, 4g+4)   (32 j-groups)
// Slot m in [0,4) holds row j = 4g + (m ^ c),  c = (s0^s2)|((s1^s2)<<1).
// Reduce over the 16-lane k-group: DPP stages xor1 (slots), xor2 (slots),
// xor15, xor8 (lanes). Lanes s<4 end holding j = 4g+s and write h.
// h padded: addr = k + (k>>3)*4 (16B aligned, <=2-way banks). Barriers are raw
// s_barrier + lgkmcnt(0); vmcnt drained once per 32-step chunk (loads 31 steps old).
__launch_bounds__(NTHR, 1)
__global__ void rnn_dpp512_kernel(const float* __restrict__ x,
                                  const float* __restrict__ Wx_w,
                                  const float* __restrict__ Wx_b,
                                  const float* __restrict__ Wh_w,
                                  const float* __restrict__ Wh_b,
                                  const float* __restrict__ fc_w,
                                  const float* __restrict__ fc_b,
                                  float* __restrict__ out) {
  const int b = blockIdx.x;
  const int tid = threadIdx.x;
  const int s = tid & 15;  // k-group (= lane&15)
  const int g = tid >> 4;  // j-group (0..31)
  const int s0 = s & 1, s1 = (s >> 1) & 1, s2 = (s >> 2) & 1;
  const int c = (s0 ^ s2) | ((s1 ^ s2) << 1);
  const int jf = 4 * g + c;                  // the j this lane finalizes
  const int jp = jf + ((jf >> 3) << 2);      // padded write index

  __shared__ __align__(16) float hA[192], hB[192];        // padded h buffers
  __shared__ __align__(16) float xsm[2][CHUNK * INSZ];    // 2 x 8KB

  // ---- weights: slot m holds row j = 4g + (m ^ c) ----
  v2f wh2[4][4], wx2[4][2];
#pragma unroll
  for (int m = 0; m < 4; ++m) {
    const int row = 4 * g + (m ^ c);
    const float* p = Wh_w + row * HID + 8 * s;
    v4f t0 = *(const v4f*)p;
    v4f t1 = *(const v4f*)(p + 4);
    wh2[m][0] = (v2f){t0.x, t0.y};
    wh2[m][1] = (v2f){t0.z, t0.w};
    wh2[m][2] = (v2f){t1.x, t1.y};
    wh2[m][3] = (v2f){t1.z, t1.w};
    const float* q = Wx_w + row * INSZ + 4 * s;
    v4f t2 = *(const v4f*)q;
    wx2[m][0] = (v2f){t2.x, t2.y};
    wx2[m][1] = (v2f){t2.z, t2.w};
  }
  const float bc = Wx_b[jf] + Wh_b[jf];

  const float* xg = x + (size_t)b * TSTEPS * INSZ;

  // ---- init h0 = 0 ----
  if (tid < 192) hA[tid] = 0.f;

  // ---- stage chunk 0: 512 threads x 16B = 8KB ----
  {
    const AS1 float* gp = (const AS1 float*)(xg + tid * 4);
    AS3 float* d = (AS3 float*)(&xsm[0][(tid >> 6) * 256]);
    __builtin_amdgcn_global_load_lds(gp, d, 16, 0, 0);
  }
  asm volatile("s_waitcnt vmcnt(0) lgkmcnt(0)\ns_barrier" ::: "memory");

  // ---- recurrence ----
  for (int tc = 0; tc < NCHUNK; ++tc) {
    // re-pin weights to arch VGPRs once per chunk (blocks AGPR shuttling)
#pragma unroll
    for (int m = 0; m < 4; ++m) {
#pragma unroll
      for (int kk = 0; kk < 4; ++kk) asm("" : "+v"(wh2[m][kk]));
#pragma unroll
      for (int kk = 0; kk < 2; ++kk) asm("" : "+v"(wx2[m][kk]));
    }
    if (tc + 1 < NCHUNK) {
      const AS1 float* gp =
          (const AS1 float*)(xg + (size_t)(tc + 1) * CHUNK * INSZ + tid * 4);
      AS3 float* d = (AS3 float*)(&xsm[(tc + 1) & 1][(tid >> 6) * 256]);
      __builtin_amdgcn_global_load_lds(gp, d, 16, 0, 0);
    }
    const float* xc = xsm[tc & 1];
    v4f xcur = *(const v4f*)&xc[4 * s];  // ts = 0 (buffer just drained)

#pragma unroll
    for (int ts = 0; ts < CHUNK; ++ts) {
      const float* hin = (ts & 1) ? hB : hA;  // parity static (CHUNK even)
      float* hout = (ts & 1) ? hA : hB;

      // h reads at step head (the only exposed LDS latency)
      const float* hp = hin + 12 * s;
      v4f h0 = *(const v4f*)hp;
      v4f h1 = *(const v4f*)(hp + 4);

      // prefetch next step's x (no h dependency; latency hidden a full step)
      v4f xnext;
      if (ts + 1 < CHUNK) xnext = *(const v4f*)&xc[(ts + 1) * INSZ + 4 * s];

      v2f xx0 = (v2f){xcur.x, xcur.y}, xx1 = (v2f){xcur.z, xcur.w};
      v2f hx0 = (v2f){h0.x, h0.y}, hx1 = (v2f){h0.z, h0.w};
      v2f hx2 = (v2f){h1.x, h1.y}, hx3 = (v2f){h1.z, h1.w};

      float a0, a1, a2, a3;
      float* aptr[4] = {&a0, &a1, &a2, &a3};
#pragma unroll
      for (int m = 0; m < 4; ++m) {
        v2f acc = pk_mul(wx2[m][0], xx0);          // x-part first (ready early)
        acc = pk_fma(wx2[m][1], xx1, acc);
        acc = pk_fma(wh2[m][0], hx0, acc);
        acc = pk_fma(wh2[m][1], hx1, acc);
        acc = pk_fma(wh2[m][2], hx2, acc);
        acc = pk_fma(wh2[m][3], hx3, acc);
        *aptr[m] = acc.x + acc.y;
      }

      // DPP butterfly reduce-scatter over the 16-lane k-group
      float b0 = a0 + dppf<DPP_XOR1>(a1);
      float b1 = a2 + dppf<DPP_XOR1>(a3);
      float w  = b0 + dppf<DPP_XOR2>(b1);
      float u  = w + dppf<DPP_XOR15>(w);
      float z  = u + dppf<DPP_XOR8>(u);

      // tanh(z+bc) = 1 - 2/(exp2(2*(z+bc)*log2e)+1)
      z += bc;
      float e = __builtin_amdgcn_exp2f(z * 2.8853900817779268f);
      float hn = fmaf(-2.f, __builtin_amdgcn_rcpf(e + 1.f), 1.f);

      if (s < 4) hout[jp] = hn;  // lanes s=0..3 hold j=4g+s

      if (ts + 1 < CHUNK) xcur = xnext;

      if (ts == CHUNK - 1) {
        // vmcnt drain folded here: next chunk's loads are 31 steps old -> free
        asm volatile("s_waitcnt vmcnt(0) lgkmcnt(0)\ns_barrier" ::: "memory");
      } else {
        asm volatile("s_waitcnt lgkmcnt(0)\ns_barrier" ::: "memory");
      }
    }
  }

  // ---- epilogue: logits + softmax over 64, one wave; final h in hA ----
  if (tid < 64) {
    float acc = fc_b[tid];
    const float* fr = fc_w + tid * HID;
#pragma unroll
    for (int k8 = 0; k8 < 16; ++k8) {
      v4f w0 = *(const v4f*)(fr + 8 * k8);
      v4f w1 = *(const v4f*)(fr + 8 * k8 + 4);
      const float* hh = &hA[12 * k8];
      v4f p0 = *(const v4f*)hh;
      v4f p1 = *(const v4f*)(hh + 4);
      acc = fmaf(w0.x, p0.x, acc);
      acc = fmaf(w0.y, p0.y, acc);
      acc = fmaf(w0.z, p0.z, acc);
      acc = fmaf(w0.w, p0.w, acc);
      acc = fmaf(w1.x, p1.x, acc);
      acc = fmaf(w1.y, p1.y, acc);
      acc = fmaf(w1.z, p1.z, acc);
      acc = fmaf(w1.w, p1.w, acc);
    }
    float m = acc;
#pragma unroll
    for (int off = 32; off >= 1; off >>= 1) m = fmaxf(m, __shfl_xor(m, off, 64));
    float e = __builtin_amdgcn_exp2f((acc - m) * 1.4426950408889634f);
    float ssum = e;
#pragma unroll
    for (int off = 32; off >= 1; off >>= 1) ssum += __shfl_xor(ssum, off, 64);
    out[b * OUTSZ + tid] = e / ssum;
  }
}

extern "C" void kernel_launch(void* const* d_in, const int* in_sizes, int n_in,
                              void* d_out, int out_size, void* d_ws, size_t ws_size,
                              hipStream_t stream) {
  const float* x    = (const float*)d_in[0];
  const float* Wx_w = (const float*)d_in[1];
  const float* Wx_b = (const float*)d_in[2];
  const float* Wh_w = (const float*)d_in[3];
  const float* Wh_b = (const float*)d_in[4];
  const float* fc_w = (const float*)d_in[5];
  const float* fc_b = (const float*)d_in[6];
  float* out = (float*)d_out;

  rnn_dpp512_kernel<<<BATCH, NTHR, 0, stream>>>(x, Wx_w, Wx_b, Wh_w, Wh_b, fc_w, fc_b, out);
}